// Round 14
// baseline (52.947 us; speedup 1.0000x reference)
//
#include <hip/hip_runtime.h>
#include <hip/hip_bf16.h>

#define N_ROWS 4096
#define D_FULL 1024
#define DHALF  512
#define GSPLIT 8

typedef __attribute__((ext_vector_type(8))) short bf16x8;
typedef __attribute__((ext_vector_type(8))) unsigned short u16x8;
typedef __attribute__((ext_vector_type(4))) float f32x4;

__device__ __forceinline__ unsigned short f2b(float f) {
  __hip_bfloat16 h = __float2bfloat16(f);
  union { __hip_bfloat16 b; unsigned short u; } cv;
  cv.b = h;
  return cv.u;
}
__device__ __forceinline__ float b2f(unsigned short u) {
  union { unsigned int i; float f; } cv;
  cv.i = ((unsigned int)u) << 16;
  return cv.f;
}

// async global -> LDS: wave-uniform LDS base, lane i lands at base + i*16B
__device__ __forceinline__ void load_lds16(const void* g, void* l) {
  __builtin_amdgcn_global_load_lds(
      (const __attribute__((address_space(1))) unsigned int*)g,
      (__attribute__((address_space(3))) unsigned int*)l, 16, 0, 0);
}

// counted vmcnt wait (literal) — never drain to 0 in the main loop
template<int N> __device__ __forceinline__ void vmwait() {
  if constexpr (N == 0)       asm volatile("s_waitcnt vmcnt(0)" ::: "memory");
  else if constexpr (N == 2)  asm volatile("s_waitcnt vmcnt(2)" ::: "memory");
  else if constexpr (N == 3)  asm volatile("s_waitcnt vmcnt(3)" ::: "memory");
  else if constexpr (N == 4)  asm volatile("s_waitcnt vmcnt(4)" ::: "memory");
  else if constexpr (N == 6)  asm volatile("s_waitcnt vmcnt(6)" ::: "memory");
  else if constexpr (N == 8)  asm volatile("s_waitcnt vmcnt(8)" ::: "memory");
  else                        asm volatile("s_waitcnt vmcnt(16)" ::: "memory");
}
__device__ __forceinline__ void barx() {
  __builtin_amdgcn_sched_barrier(0);
  __builtin_amdgcn_s_barrier();
  __builtin_amdgcn_sched_barrier(0);
}
__device__ __forceinline__ int b4inc(int b) { return (b + 1) & 3; }

// ================= fused conversion =================
__device__ __forceinline__ void cvt_tile(const float* __restrict__ src, int lds_,
                                         unsigned short* __restrict__ dst, int ldd,
                                         unsigned short* __restrict__ dstT, int ldt,
                                         int n0, int c0) {
  __shared__ unsigned short tile[64][66];
  const int t  = threadIdx.x;
  const int r  = t >> 2;
  const int cq = (t & 3) * 16;

  unsigned short loc[16];
  #pragma unroll
  for (int i = 0; i < 4; ++i) {
    float4 v = *reinterpret_cast<const float4*>(&src[(size_t)(n0 + r) * lds_ + c0 + cq + i * 4]);
    loc[i*4+0] = f2b(v.x); loc[i*4+1] = f2b(v.y); loc[i*4+2] = f2b(v.z); loc[i*4+3] = f2b(v.w);
  }
  if (dst) {
    u16x8 a, b;
    #pragma unroll
    for (int i = 0; i < 8; ++i) { a[i] = loc[i]; b[i] = loc[8+i]; }
    unsigned short* p = &dst[(size_t)(n0 + r) * ldd + c0 + cq];
    *reinterpret_cast<u16x8*>(p)     = a;
    *reinterpret_cast<u16x8*>(p + 8) = b;
  }
  if (dstT) {
    #pragma unroll
    for (int i = 0; i < 8; ++i) {
      ushort2 w2; w2.x = loc[2*i]; w2.y = loc[2*i+1];
      *reinterpret_cast<ushort2*>(&tile[r][cq + 2*i]) = w2;
    }
    __syncthreads();
    const int c  = t >> 2;
    const int ng = (t & 3) * 16;
    unsigned short o[16];
    #pragma unroll
    for (int i = 0; i < 16; ++i) o[i] = tile[ng + i][c];
    u16x8 a, b;
    #pragma unroll
    for (int i = 0; i < 8; ++i) { a[i] = o[i]; b[i] = o[8+i]; }
    unsigned short* p = &dstT[(size_t)(c0 + c) * ldt + n0 + ng];
    *reinterpret_cast<u16x8*>(p)     = a;
    *reinterpret_cast<u16x8*>(p + 8) = b;
  }
}

__global__ __launch_bounds__(256) void k_cvt_all(const float* __restrict__ x,
                                                 const float* __restrict__ w0, const float* __restrict__ w1,
                                                 const float* __restrict__ w2, const float* __restrict__ w3,
                                                 const float* __restrict__ w4, const float* __restrict__ w5,
                                                 unsigned short* __restrict__ xb,
                                                 unsigned short* __restrict__ xT,
                                                 unsigned short* __restrict__ Wb,
                                                 unsigned short* __restrict__ WbT) {
  const int b = blockIdx.x;
  if (b < 1024) {
    cvt_tile(x, D_FULL, xb, D_FULL, xT, N_ROWS, (b >> 4) * 64, (b & 15) * 64);
  } else {
    const int b2 = b - 1024;
    const int z = b2 >> 6, t = b2 & 63;
    const float* w;
    switch (z) {
      case 0: w = w0; break; case 1: w = w1; break; case 2: w = w2; break;
      case 3: w = w3; break; case 4: w = w4; break; default: w = w5; break;
    }
    const size_t HH = (size_t)DHALF * DHALF;
    unsigned short* d  = (z >= 4) ? (Wb  + z * HH) : nullptr;
    unsigned short* dT = (z <  4) ? (WbT + z * HH) : nullptr;
    cvt_tile(w, DHALF, d, DHALF, dT, DHALF, (t >> 3) * 64, (t & 7) * 64);
  }
}

// ================= gram (upper-triangle, diag-dedup) + P; 4-buf, 1 barrier/iter; 192 blocks =================
__global__ __launch_bounds__(256) void k_gp(const unsigned short* __restrict__ xT,
                                            const unsigned short* __restrict__ WbT,
                                            unsigned short* __restrict__ Gp,
                                            unsigned short* __restrict__ P) {
  const int o = blockIdx.x;
  const int c = o & 7, j = o >> 3;

  const unsigned short* Ab;
  const unsigned short* Bb;
  unsigned short* Cb;
  int lda, m0, n0;
  bool sameAB = false;
  const long long HH = 262144;
  if (j < 4) {
    const int pp = c * 4 + j;
    const int h = pp >> 4, tile = pp & 15;
    Ab = WbT + (size_t)h * HH;
    Bb = WbT + (size_t)(2 + h) * HH;
    Cb = P + (size_t)h * HH;
    lda = DHALF;
    m0 = (tile >> 2) * 128; n0 = (tile & 3) * 128;
  } else {
    const int g = c * 20 + (j - 4);
    const int slice = g / 10, p = g - slice * 10;
    const int h = slice >> 3, s = slice & 7;
    const int ti = (p < 4) ? 0 : (p < 7) ? 1 : (p < 9) ? 2 : 3;
    const int tj = (p < 4) ? p : (p < 7) ? p - 3 : (p < 9) ? p - 5 : 3;
    Ab = xT + (size_t)h * DHALF * N_ROWS + s * (N_ROWS / GSPLIT);
    Bb = Ab;
    Cb = Gp + (size_t)slice * HH;
    lda = N_ROWS;
    m0 = ti * 128; n0 = tj * 128;
    sameAB = (ti == tj);
  }

  __shared__ __align__(16) unsigned short lds[4][2][128 * 32];   // 64 KB

  const int tid  = threadIdx.x;
  const int lane = tid & 63;
  const int wave = tid >> 6;
  const int wm = (wave >> 1) * 64;
  const int wn = (wave & 1) * 64;
  const int fr = lane & 15;
  const int kg = (lane >> 4) * 8;

  const int srow = wave * 32 + (lane >> 2);
  const int scol = (lane & 3) * 8;
  const unsigned short* gA0 = Ab + (size_t)(m0 + srow) * lda + scol;
  const unsigned short* gA1 = gA0 + (size_t)16 * lda;
  const unsigned short* gB0 = Bb + (size_t)(n0 + srow) * lda + scol;
  const unsigned short* gB1 = gB0 + (size_t)16 * lda;
  const int stOff = wave * 1024;

  f32x4 acc[4][4] = {};

  auto STAGE = [&](int buf, int t) {
    const int kofs = t * 32;
    load_lds16(gA0 + kofs, &lds[buf][0][stOff]);
    load_lds16(gA1 + kofs, &lds[buf][0][stOff + 512]);
    if (!sameAB) {
      load_lds16(gB0 + kofs, &lds[buf][1][stOff]);
      load_lds16(gB1 + kofs, &lds[buf][1][stOff + 512]);
    }
  };
  auto COMPUTE = [&](int buf) {
    const unsigned short* la = &lds[buf][0][0];
    const unsigned short* lb = sameAB ? la : &lds[buf][1][0];
    bf16x8 af[4], bf[4];
    #pragma unroll
    for (int f = 0; f < 4; ++f) {
      af[f] = *reinterpret_cast<const bf16x8*>(&la[(wm + f * 16 + fr) * 32 + kg]);
      bf[f] = *reinterpret_cast<const bf16x8*>(&lb[(wn + f * 16 + fr) * 32 + kg]);
    }
    #pragma unroll
    for (int fm = 0; fm < 4; ++fm)
      #pragma unroll
      for (int fn = 0; fn < 4; ++fn)
        acc[fm][fn] = __builtin_amdgcn_mfma_f32_16x16x32_bf16(af[fm], bf[fn], acc[fm][fn], 0, 0, 0);
  };

  STAGE(0, 0); STAGE(1, 1);
  int bufS = 2, bufC = 0;
  if (sameAB) {
    for (int t = 0; t < 14; ++t) {
      STAGE(bufS, t + 2); bufS = b4inc(bufS);
      vmwait<4>(); barx();
      COMPUTE(bufC); bufC = b4inc(bufC);
    }
    vmwait<2>(); barx();
    COMPUTE(bufC); bufC = b4inc(bufC);
    vmwait<0>(); barx();
    COMPUTE(bufC);
  } else {
    for (int t = 0; t < 14; ++t) {
      STAGE(bufS, t + 2); bufS = b4inc(bufS);
      vmwait<8>(); barx();
      COMPUTE(bufC); bufC = b4inc(bufC);
    }
    vmwait<4>(); barx();
    COMPUTE(bufC); bufC = b4inc(bufC);
    vmwait<0>(); barx();
    COMPUTE(bufC);
  }

  #pragma unroll
  for (int fm = 0; fm < 4; ++fm)
    #pragma unroll
    for (int fn = 0; fn < 4; ++fn)
      #pragma unroll
      for (int r = 0; r < 4; ++r) {
        int row = m0 + wm + fm * 16 + (lane >> 4) * 4 + r;
        int col = n0 + wn + fn * 16 + fr;
        Cb[(size_t)row * DHALF + col] = f2b(acc[fm][fn][r]);
      }
}

// ================= TT = Wv * G with inline Gp reduction (replaces gred + k_s#1) =================
// 128 blocks. Phase A: reduce B-panel G[n0..n0+64][0..512] from Gp (upper-tile storage,
// symmetric reconstruction) into LDS Bp[64][520]. Phase B: GEMM, A=Wv 4-buf pipelined, B from Bp.
__global__ __launch_bounds__(256) void k_tt(const unsigned short* __restrict__ Wv,
                                            const unsigned short* __restrict__ Gp,
                                            unsigned short* __restrict__ TT) {
  const int o   = blockIdx.x;
  const int swz = (o & 7) * 16 + (o >> 3);
  const int bx = swz & 7, by = (swz >> 3) & 7, bz = swz >> 6;

  const unsigned short* Ab = Wv + (size_t)bz * 262144;
  unsigned short* Cb = TT + (size_t)bz * 262144;
  const int n0 = bx * 64;
  const int m0 = by * 64;
  const int tn = bx >> 1;                 // n-tile (128 unit) of the B panel
  const size_t HH = 262144;
  const unsigned short* gpBase = Gp + (size_t)bz * GSPLIT * HH;

  __shared__ __align__(16) unsigned short Bp[64 * 520];          // 66.56 KB (padded rows)
  __shared__ __align__(16) unsigned short lds[4][4][64 * 32];    // A bufs: 4 x 4panels x 4KB = 64 KB
  __shared__ unsigned short T[32][66];                           // 4.2 KB

  const int tid  = threadIdx.x;
  const int lane = tid & 63;
  const int wave = tid >> 6;
  const int wm = (wave >> 1) * 32;
  const int wn = (wave & 1) * 32;
  const int fr = lane & 15;
  const int kg = (lane >> 4) * 8;

  // A staging geometry (same as proven k_s A-side): wave stages panel `wave` (k-sub [wave*32,+32))
  const int srow = lane >> 2;
  const int scol = (lane & 3) * 8;
  const unsigned short* gA = Ab + (size_t)(m0 + srow) * DHALF + wave * 32 + scol;

  auto STAGE = [&](int buf, int t) {      // 4 loads/wave
    const int kofs = t * 128;
    #pragma unroll
    for (int j = 0; j < 4; ++j)
      load_lds16(gA + kofs + j * 16 * DHALF, &lds[buf][wave][j * 512]);
  };

  // issue first two A bufs early; they fly during phase A
  STAGE(0, 0); STAGE(1, 1);

  // ---- Phase A: reduce B panel ----
  for (int kc = 0; kc < 4; ++kc) {
    if (tn <= kc) {
      // direct: element (n0+r, kc*128+c) stored at Gp[s][n0+r][kc*128+c]
      const int r  = tid >> 2;
      const int c0 = (tid & 3) * 32;
      float s0[32];
      #pragma unroll
      for (int i = 0; i < 32; ++i) s0[i] = 0.f;
      for (int s = 0; s < GSPLIT; ++s) {
        const unsigned short* p = gpBase + (size_t)s * HH + (size_t)(n0 + r) * DHALF + kc * 128 + c0;
        #pragma unroll
        for (int jq = 0; jq < 4; ++jq) {
          u16x8 v = *reinterpret_cast<const u16x8*>(p + jq * 8);
          #pragma unroll
          for (int i = 0; i < 8; ++i) s0[jq * 8 + i] += b2f(v[i]);
        }
      }
      #pragma unroll
      for (int jq = 0; jq < 4; ++jq) {
        u16x8 o8;
        #pragma unroll
        for (int i = 0; i < 8; ++i) o8[i] = f2b(s0[jq * 8 + i]);
        *reinterpret_cast<u16x8*>(&Bp[r * 520 + kc * 128 + c0 + jq * 8]) = o8;
      }
    } else {
      // lower: element (n, k) stored at Gp[s][k][n]; 4 sub-passes of 32 source rows
      for (int sp = 0; sp < 4; ++sp) {
        const int rr = sp * 32 + (tid >> 3);      // source row (k index within chunk base)
        const int cc = (tid & 7) * 8;             // source col (n offset)
        float s0[8] = {};
        for (int s = 0; s < GSPLIT; ++s) {
          u16x8 v = *reinterpret_cast<const u16x8*>(
              gpBase + (size_t)s * HH + (size_t)(kc * 128 + rr) * DHALF + n0 + cc);
          #pragma unroll
          for (int i = 0; i < 8; ++i) s0[i] += b2f(v[i]);
        }
        #pragma unroll
        for (int i = 0; i < 8; ++i) T[tid >> 3][cc + i] = f2b(s0[i]);
        __syncthreads();
        const int nn = tid >> 2;                  // output row (n)
        const int k8 = (tid & 3) * 8;             // output col group (k within sub-pass)
        u16x8 o8;
        #pragma unroll
        for (int i = 0; i < 8; ++i) o8[i] = T[k8 + i][nn];
        *reinterpret_cast<u16x8*>(&Bp[nn * 520 + kc * 128 + sp * 32 + k8]) = o8;
        __syncthreads();
      }
    }
  }
  __syncthreads();   // Bp published

  // ---- Phase B: GEMM, 4-buf A pipeline, B from Bp ----
  f32x4 acc[2][2] = {};

  auto COMPUTE = [&](int buf, int tk) {
    #pragma unroll
    for (int p = 0; p < 4; ++p) {
      const int kb = tk * 128 + p * 32;
      bf16x8 a0 = *reinterpret_cast<const bf16x8*>(&lds[buf][p][(wm + fr) * 32 + kg]);
      bf16x8 a1 = *reinterpret_cast<const bf16x8*>(&lds[buf][p][(wm + 16 + fr) * 32 + kg]);
      bf16x8 b0 = *reinterpret_cast<const bf16x8*>(&Bp[(wn + fr) * 520 + kb + kg]);
      bf16x8 b1 = *reinterpret_cast<const bf16x8*>(&Bp[(wn + 16 + fr) * 520 + kb + kg]);
      acc[0][0] = __builtin_amdgcn_mfma_f32_16x16x32_bf16(a0, b0, acc[0][0], 0, 0, 0);
      acc[0][1] = __builtin_amdgcn_mfma_f32_16x16x32_bf16(a0, b1, acc[0][1], 0, 0, 0);
      acc[1][0] = __builtin_amdgcn_mfma_f32_16x16x32_bf16(a1, b0, acc[1][0], 0, 0, 0);
      acc[1][1] = __builtin_amdgcn_mfma_f32_16x16x32_bf16(a1, b1, acc[1][1], 0, 0, 0);
    }
  };

  int bufS = 2, bufC = 0;
  for (int t = 0; t < 2; ++t) {           // nt = 4, ONE barrier/iter
    STAGE(bufS, t + 2); bufS = b4inc(bufS);
    vmwait<8>(); barx();
    COMPUTE(bufC, t); bufC = b4inc(bufC);
  }
  vmwait<4>(); barx();
  COMPUTE(bufC, 2); bufC = b4inc(bufC);
  vmwait<0>(); barx();
  COMPUTE(bufC, 3);

  #pragma unroll
  for (int fm = 0; fm < 2; ++fm)
    #pragma unroll
    for (int fn = 0; fn < 2; ++fn)
      #pragma unroll
      for (int r = 0; r < 4; ++r) {
        int row = m0 + wm + fm * 16 + (lane >> 4) * 4 + r;
        int col = n0 + wn + fn * 16 + fr;
        Cb[(size_t)row * DHALF + col] = f2b(acc[fm][fn][r]);
      }
}

// ================= small GEMM 512^3: 4-buf, 1 barrier/iter, BK=128, nt=4 (MT = TT * P^T) =================
__global__ __launch_bounds__(256) void k_s(const unsigned short* __restrict__ A,
                                           const unsigned short* __restrict__ B,
                                           unsigned short* __restrict__ C,
                                           long long hA, long long hB, long long hC) {
  const int o   = blockIdx.x + blockIdx.y * 8 + blockIdx.z * 64;
  const int swz = (o & 7) * 16 + (o >> 3);
  const int bx = swz & 7, by = (swz >> 3) & 7, bz = swz >> 6;

  const unsigned short* Ab = A + (size_t)bz * hA;
  const unsigned short* Bb = B + (size_t)bz * hB;
  unsigned short* Cb = C + (size_t)bz * hC;
  const int n0 = bx * 64;
  const int m0 = by * 64;

  __shared__ __align__(16) unsigned short lds[4][2][4][64 * 32];   // 128 KB

  const int tid  = threadIdx.x;
  const int lane = tid & 63;
  const int wave = tid >> 6;
  const int wm = (wave >> 1) * 32;
  const int wn = (wave & 1) * 32;
  const int fr = lane & 15;
  const int kg = (lane >> 4) * 8;

  const int srow = lane >> 2;
  const int scol = (lane & 3) * 8;
  const unsigned short* gA = Ab + (size_t)(m0 + srow) * DHALF + wave * 32 + scol;
  const unsigned short* gB = Bb + (size_t)(n0 + srow) * DHALF + wave * 32 + scol;

  f32x4 acc[2][2] = {};

  auto STAGE = [&](int buf, int t) {      // 8 loads/wave
    const int kofs = t * 128;
    #pragma unroll
    for (int j = 0; j < 4; ++j) {
      load_lds16(gA + kofs + j * 16 * DHALF, &lds[buf][0][wave][j * 512]);
      load_lds16(gB + kofs + j * 16 * DHALF, &lds[buf][1][wave][j * 512]);
    }
  };
  auto COMPUTE = [&](int buf) {
    #pragma unroll
    for (int p = 0; p < 4; ++p) {
      bf16x8 a0 = *reinterpret_cast<const bf16x8*>(&lds[buf][0][p][(wm + fr) * 32 + kg]);
      bf16x8 a1 = *reinterpret_cast<const bf16x8*>(&lds[buf][0][p][(wm + 16 + fr) * 32 + kg]);
      bf16x8 b0 = *reinterpret_cast<const bf16x8*>(&lds[buf][1][p][(wn + fr) * 32 + kg]);
      bf16x8 b1 = *reinterpret_cast<const bf16x8*>(&lds[buf][1][p][(wn + 16 + fr) * 32 + kg]);
      acc[0][0] = __builtin_amdgcn_mfma_f32_16x16x32_bf16(a0, b0, acc[0][0], 0, 0, 0);
      acc[0][1] = __builtin_amdgcn_mfma_f32_16x16x32_bf16(a0, b1, acc[0][1], 0, 0, 0);
      acc[1][0] = __builtin_amdgcn_mfma_f32_16x16x32_bf16(a1, b0, acc[1][0], 0, 0, 0);
      acc[1][1] = __builtin_amdgcn_mfma_f32_16x16x32_bf16(a1, b1, acc[1][1], 0, 0, 0);
    }
  };

  STAGE(0, 0); STAGE(1, 1);
  int bufS = 2, bufC = 0;
  for (int t = 0; t < 2; ++t) {
    STAGE(bufS, t + 2); bufS = b4inc(bufS);
    vmwait<16>(); barx();
    COMPUTE(bufC); bufC = b4inc(bufC);
  }
  vmwait<8>(); barx();
  COMPUTE(bufC); bufC = b4inc(bufC);
  vmwait<0>(); barx();
  COMPUTE(bufC);

  #pragma unroll
  for (int fm = 0; fm < 2; ++fm)
    #pragma unroll
    for (int fn = 0; fn < 2; ++fn)
      #pragma unroll
      for (int r = 0; r < 4; ++r) {
        int row = m0 + wm + fm * 16 + (lane >> 4) * 4 + r;
        int col = n0 + wn + fn * 16 + fr;
        Cb[(size_t)row * DHALF + col] = f2b(acc[fm][fn][r]);
      }
}

// ================= final: out = X_h * M_h; 128x64 tiles, 512 blocks; 4-buf, 1 barrier/iter =================
__global__ __launch_bounds__(256) void k_final(const unsigned short* __restrict__ xb,
                                               const unsigned short* __restrict__ MT,
                                               float* __restrict__ out) {
  const int o   = blockIdx.x + blockIdx.y * 8 + blockIdx.z * 256;
  const int swz = (o & 7) * 64 + (o >> 3);
  const int bx = swz & 7, by = (swz >> 3) & 31, bz = swz >> 8;

  const unsigned short* MTh = MT + (size_t)bz * 262144;
  const int hoff = bz * DHALF;
  const int n0 = bx * 64;
  const int m0 = by * 128;

  __shared__ __align__(16) unsigned short SH[4][6144];  // per buf: A 4096 + B 2048 (48 KB)

  const int tid  = threadIdx.x;
  const int lane = tid & 63;
  const int wave = tid >> 6;
  const int wm = (wave >> 1) * 64;
  const int wn = (wave & 1) * 32;
  const int fr = lane & 15;
  const int kg = (lane >> 4) * 8;

  const int srow = wave * 32 + (lane >> 2);
  const int scol = (lane & 3) * 8;
  const unsigned short* gA0 = xb + (size_t)(m0 + srow) * D_FULL + hoff + scol;
  const unsigned short* gA1 = gA0 + (size_t)16 * D_FULL;
  const int brow = wave * 16 + (lane >> 2);
  const unsigned short* gB = MTh + (size_t)(n0 + brow) * DHALF + scol;

  f32x4 acc[4][2] = {};

  auto STAGE = [&](int buf, int t) {      // 3 loads/wave
    const int kofs = t * 32;
    unsigned short* Abuf = &SH[buf][0];
    unsigned short* Bbuf = &SH[buf][4096];
    load_lds16(gA0 + kofs, Abuf + wave * 1024);
    load_lds16(gA1 + kofs, Abuf + wave * 1024 + 512);
    load_lds16(gB + kofs, Bbuf + wave * 512);
  };
  auto COMPUTE = [&](int buf) {
    unsigned short* Abuf = &SH[buf][0];
    unsigned short* Bbuf = &SH[buf][4096];
    bf16x8 af[4], bv[2];
    #pragma unroll
    for (int f = 0; f < 4; ++f)
      af[f] = *reinterpret_cast<const bf16x8*>(&Abuf[(wm + f * 16 + fr) * 32 + kg]);
    #pragma unroll
    for (int f = 0; f < 2; ++f)
      bv[f] = *reinterpret_cast<const bf16x8*>(&Bbuf[(wn + f * 16 + fr) * 32 + kg]);
    #pragma unroll
    for (int fm = 0; fm < 4; ++fm)
      #pragma unroll
      for (int fn = 0; fn < 2; ++fn)
        acc[fm][fn] = __builtin_amdgcn_mfma_f32_16x16x32_bf16(af[fm], bv[fn], acc[fm][fn], 0, 0, 0);
  };

  STAGE(0, 0); STAGE(1, 1);
  int bufS = 2, bufC = 0;
  for (int t = 0; t < 14; ++t) {          // nt = 16, ONE barrier/iter
    STAGE(bufS, t + 2); bufS = b4inc(bufS);
    vmwait<6>(); barx();
    COMPUTE(bufC); bufC = b4inc(bufC);
  }
  vmwait<3>(); barx();
  COMPUTE(bufC); bufC = b4inc(bufC);
  vmwait<0>(); barx();
  COMPUTE(bufC);

  #pragma unroll
  for (int fm = 0; fm < 4; ++fm)
    #pragma unroll
    for (int fn = 0; fn < 2; ++fn)
      #pragma unroll
      for (int r = 0; r < 4; ++r) {
        int row = m0 + wm + fm * 16 + (lane >> 4) * 4 + r;
        int col = hoff + n0 + wn + fn * 16 + fr;
        out[(size_t)row * D_FULL + col] = acc[fm][fn][r];
      }
}

extern "C" void kernel_launch(void* const* d_in, const int* in_sizes, int n_in,
                              void* d_out, int out_size, void* d_ws, size_t ws_size,
                              hipStream_t stream) {
  const float* x   = (const float*)d_in[0];
  const float* Wq1 = (const float*)d_in[1];
  const float* Wq2 = (const float*)d_in[2];
  const float* Wk1 = (const float*)d_in[3];
  const float* Wk2 = (const float*)d_in[4];
  const float* Wv1 = (const float*)d_in[5];
  const float* Wv2 = (const float*)d_in[6];
  float* out = (float*)d_out;

  // workspace layout (ushort elements), ~36 MB
  unsigned short* ws  = (unsigned short*)d_ws;
  unsigned short* xb  = ws;                    // [4096][1024]
  unsigned short* xT  = ws + 4194304;          // [1024][4096]
  unsigned short* Wb  = ws + 8388608;          // 6x[512][512] (only v written)
  unsigned short* WbT = ws + 9961472;          // transposes (only q,k written)
  unsigned short* P   = ws + 12058624;         // [2][512][512]
  unsigned short* TT  = ws + 12582912;         // [2][512][512]
  unsigned short* MT  = ws + 13107200;         // [2][512][512]
  unsigned short* Gp  = ws + 13631488;         // [2*GSPLIT][512][512] bf16 partials (upper tiles only)

  const long long HH = 262144;

  k_cvt_all<<<1408, 256, 0, stream>>>(x, Wq1, Wq2, Wk1, Wk2, Wv1, Wv2, xb, xT, Wb, WbT);

  // P (4 per XCD chunk, first) + gram upper-triangle pairs (20 per chunk); 192 blocks
  k_gp<<<192, 256, 0, stream>>>(xT, WbT, Gp, P);

  // TT = Wv * G with inline Gp reduction (replaces gred + first small GEMM)
  k_tt<<<128, 256, 0, stream>>>(Wb + 4 * HH, Gp, TT);

  // MT = TT * P^T
  k_s<<<dim3(8, 8, 2), 256, 0, stream>>>(TT, P, MT, HH, HH, HH);

  // out = X_h * M_h  (128x64 tiles, 2 blocks/CU)
  k_final<<<dim3(8, 32, 2), 256, 0, stream>>>(xb, MT, out);
}

// Round 15
// 43.958 us; speedup vs baseline: 1.2045x; 1.2045x over previous
//
#include <hip/hip_runtime.h>
#include <hip/hip_bf16.h>

#define N_ROWS 4096
#define D_FULL 1024
#define DHALF  512
#define GSPLIT 8

typedef __attribute__((ext_vector_type(8))) short bf16x8;
typedef __attribute__((ext_vector_type(8))) unsigned short u16x8;
typedef __attribute__((ext_vector_type(4))) float f32x4;

__device__ __forceinline__ unsigned short f2b(float f) {
  __hip_bfloat16 h = __float2bfloat16(f);
  union { __hip_bfloat16 b; unsigned short u; } cv;
  cv.b = h;
  return cv.u;
}
__device__ __forceinline__ float b2f(unsigned short u) {
  union { unsigned int i; float f; } cv;
  cv.i = ((unsigned int)u) << 16;
  return cv.f;
}

// async global -> LDS: wave-uniform LDS base, lane i lands at base + i*16B
__device__ __forceinline__ void load_lds16(const void* g, void* l) {
  __builtin_amdgcn_global_load_lds(
      (const __attribute__((address_space(1))) unsigned int*)g,
      (__attribute__((address_space(3))) unsigned int*)l, 16, 0, 0);
}

// counted vmcnt wait (literal) — never drain to 0 in the main loop
template<int N> __device__ __forceinline__ void vmwait() {
  if constexpr (N == 0)       asm volatile("s_waitcnt vmcnt(0)" ::: "memory");
  else if constexpr (N == 2)  asm volatile("s_waitcnt vmcnt(2)" ::: "memory");
  else if constexpr (N == 3)  asm volatile("s_waitcnt vmcnt(3)" ::: "memory");
  else if constexpr (N == 4)  asm volatile("s_waitcnt vmcnt(4)" ::: "memory");
  else if constexpr (N == 6)  asm volatile("s_waitcnt vmcnt(6)" ::: "memory");
  else if constexpr (N == 8)  asm volatile("s_waitcnt vmcnt(8)" ::: "memory");
  else                        asm volatile("s_waitcnt vmcnt(16)" ::: "memory");
}
__device__ __forceinline__ void barx() {
  __builtin_amdgcn_sched_barrier(0);
  __builtin_amdgcn_s_barrier();
  __builtin_amdgcn_sched_barrier(0);
}
__device__ __forceinline__ int b4inc(int b) { return (b + 1) & 3; }

// ================= fused conversion =================
__device__ __forceinline__ void cvt_tile(const float* __restrict__ src, int lds_,
                                         unsigned short* __restrict__ dst, int ldd,
                                         unsigned short* __restrict__ dstT, int ldt,
                                         int n0, int c0) {
  __shared__ unsigned short tile[64][66];
  const int t  = threadIdx.x;
  const int r  = t >> 2;
  const int cq = (t & 3) * 16;

  unsigned short loc[16];
  #pragma unroll
  for (int i = 0; i < 4; ++i) {
    float4 v = *reinterpret_cast<const float4*>(&src[(size_t)(n0 + r) * lds_ + c0 + cq + i * 4]);
    loc[i*4+0] = f2b(v.x); loc[i*4+1] = f2b(v.y); loc[i*4+2] = f2b(v.z); loc[i*4+3] = f2b(v.w);
  }
  if (dst) {
    u16x8 a, b;
    #pragma unroll
    for (int i = 0; i < 8; ++i) { a[i] = loc[i]; b[i] = loc[8+i]; }
    unsigned short* p = &dst[(size_t)(n0 + r) * ldd + c0 + cq];
    *reinterpret_cast<u16x8*>(p)     = a;
    *reinterpret_cast<u16x8*>(p + 8) = b;
  }
  if (dstT) {
    #pragma unroll
    for (int i = 0; i < 8; ++i) {
      ushort2 w2; w2.x = loc[2*i]; w2.y = loc[2*i+1];
      *reinterpret_cast<ushort2*>(&tile[r][cq + 2*i]) = w2;
    }
    __syncthreads();
    const int c  = t >> 2;
    const int ng = (t & 3) * 16;
    unsigned short o[16];
    #pragma unroll
    for (int i = 0; i < 16; ++i) o[i] = tile[ng + i][c];
    u16x8 a, b;
    #pragma unroll
    for (int i = 0; i < 8; ++i) { a[i] = o[i]; b[i] = o[8+i]; }
    unsigned short* p = &dstT[(size_t)(c0 + c) * ldt + n0 + ng];
    *reinterpret_cast<u16x8*>(p)     = a;
    *reinterpret_cast<u16x8*>(p + 8) = b;
  }
}

__global__ __launch_bounds__(256) void k_cvt_all(const float* __restrict__ x,
                                                 const float* __restrict__ w0, const float* __restrict__ w1,
                                                 const float* __restrict__ w2, const float* __restrict__ w3,
                                                 const float* __restrict__ w4, const float* __restrict__ w5,
                                                 unsigned short* __restrict__ xb,
                                                 unsigned short* __restrict__ xT,
                                                 unsigned short* __restrict__ Wb,
                                                 unsigned short* __restrict__ WbT) {
  const int b = blockIdx.x;
  if (b < 1024) {
    cvt_tile(x, D_FULL, xb, D_FULL, xT, N_ROWS, (b >> 4) * 64, (b & 15) * 64);
  } else {
    const int b2 = b - 1024;
    const int z = b2 >> 6, t = b2 & 63;
    const float* w;
    switch (z) {
      case 0: w = w0; break; case 1: w = w1; break; case 2: w = w2; break;
      case 3: w = w3; break; case 4: w = w4; break; default: w = w5; break;
    }
    const size_t HH = (size_t)DHALF * DHALF;
    unsigned short* d  = (z >= 4) ? (Wb  + z * HH) : nullptr;
    unsigned short* dT = (z <  4) ? (WbT + z * HH) : nullptr;
    cvt_tile(w, DHALF, d, DHALF, dT, DHALF, (t >> 3) * 64, (t & 7) * 64);
  }
}

// ================= gram (upper-triangle, diag-dedup) + P; 4-buf, 1 barrier/iter; 192 blocks =================
__global__ __launch_bounds__(256) void k_gp(const unsigned short* __restrict__ xT,
                                            const unsigned short* __restrict__ WbT,
                                            unsigned short* __restrict__ Gp,
                                            unsigned short* __restrict__ P) {
  const int o = blockIdx.x;
  const int c = o & 7, j = o >> 3;

  const unsigned short* Ab;
  const unsigned short* Bb;
  unsigned short* Cb;
  int lda, m0, n0;
  bool sameAB = false;
  const long long HH = 262144;
  if (j < 4) {
    const int pp = c * 4 + j;
    const int h = pp >> 4, tile = pp & 15;
    Ab = WbT + (size_t)h * HH;
    Bb = WbT + (size_t)(2 + h) * HH;
    Cb = P + (size_t)h * HH;
    lda = DHALF;
    m0 = (tile >> 2) * 128; n0 = (tile & 3) * 128;
  } else {
    const int g = c * 20 + (j - 4);
    const int slice = g / 10, p = g - slice * 10;
    const int h = slice >> 3, s = slice & 7;
    const int ti = (p < 4) ? 0 : (p < 7) ? 1 : (p < 9) ? 2 : 3;
    const int tj = (p < 4) ? p : (p < 7) ? p - 3 : (p < 9) ? p - 5 : 3;
    Ab = xT + (size_t)h * DHALF * N_ROWS + s * (N_ROWS / GSPLIT);
    Bb = Ab;
    Cb = Gp + (size_t)slice * HH;
    lda = N_ROWS;
    m0 = ti * 128; n0 = tj * 128;
    sameAB = (ti == tj);
  }

  __shared__ __align__(16) unsigned short lds[4][2][128 * 32];   // 64 KB

  const int tid  = threadIdx.x;
  const int lane = tid & 63;
  const int wave = tid >> 6;
  const int wm = (wave >> 1) * 64;
  const int wn = (wave & 1) * 64;
  const int fr = lane & 15;
  const int kg = (lane >> 4) * 8;

  const int srow = wave * 32 + (lane >> 2);
  const int scol = (lane & 3) * 8;
  const unsigned short* gA0 = Ab + (size_t)(m0 + srow) * lda + scol;
  const unsigned short* gA1 = gA0 + (size_t)16 * lda;
  const unsigned short* gB0 = Bb + (size_t)(n0 + srow) * lda + scol;
  const unsigned short* gB1 = gB0 + (size_t)16 * lda;
  const int stOff = wave * 1024;

  f32x4 acc[4][4] = {};

  auto STAGE = [&](int buf, int t) {
    const int kofs = t * 32;
    load_lds16(gA0 + kofs, &lds[buf][0][stOff]);
    load_lds16(gA1 + kofs, &lds[buf][0][stOff + 512]);
    if (!sameAB) {
      load_lds16(gB0 + kofs, &lds[buf][1][stOff]);
      load_lds16(gB1 + kofs, &lds[buf][1][stOff + 512]);
    }
  };
  auto COMPUTE = [&](int buf) {
    const unsigned short* la = &lds[buf][0][0];
    const unsigned short* lb = sameAB ? la : &lds[buf][1][0];
    bf16x8 af[4], bf[4];
    #pragma unroll
    for (int f = 0; f < 4; ++f) {
      af[f] = *reinterpret_cast<const bf16x8*>(&la[(wm + f * 16 + fr) * 32 + kg]);
      bf[f] = *reinterpret_cast<const bf16x8*>(&lb[(wn + f * 16 + fr) * 32 + kg]);
    }
    #pragma unroll
    for (int fm = 0; fm < 4; ++fm)
      #pragma unroll
      for (int fn = 0; fn < 4; ++fn)
        acc[fm][fn] = __builtin_amdgcn_mfma_f32_16x16x32_bf16(af[fm], bf[fn], acc[fm][fn], 0, 0, 0);
  };

  STAGE(0, 0); STAGE(1, 1);
  int bufS = 2, bufC = 0;
  if (sameAB) {
    for (int t = 0; t < 14; ++t) {        // nt = 16, ONE barrier/iter
      STAGE(bufS, t + 2); bufS = b4inc(bufS);
      vmwait<4>(); barx();
      COMPUTE(bufC); bufC = b4inc(bufC);
    }
    vmwait<2>(); barx();
    COMPUTE(bufC); bufC = b4inc(bufC);
    vmwait<0>(); barx();
    COMPUTE(bufC);
  } else {
    for (int t = 0; t < 14; ++t) {
      STAGE(bufS, t + 2); bufS = b4inc(bufS);
      vmwait<8>(); barx();
      COMPUTE(bufC); bufC = b4inc(bufC);
    }
    vmwait<4>(); barx();
    COMPUTE(bufC); bufC = b4inc(bufC);
    vmwait<0>(); barx();
    COMPUTE(bufC);
  }

  #pragma unroll
  for (int fm = 0; fm < 4; ++fm)
    #pragma unroll
    for (int fn = 0; fn < 4; ++fn)
      #pragma unroll
      for (int r = 0; r < 4; ++r) {
        int row = m0 + wm + fm * 16 + (lane >> 4) * 4 + r;
        int col = n0 + wn + fn * 16 + fr;
        Cb[(size_t)row * DHALF + col] = f2b(acc[fm][fn][r]);
      }
}

// ================= reduce partials -> G (256 blocks, 64x32 subtiles) =================
__global__ __launch_bounds__(256) void k_gred(const unsigned short* __restrict__ Gp,
                                              unsigned short* __restrict__ G) {
  __shared__ unsigned short T[32][66];
  const int b   = blockIdx.x;
  const int h   = b >> 7;
  const int sub = b & 127;
  const int sr  = sub >> 4, sc = sub & 15;
  const int ti  = sr >> 1,  tj = sc >> 2;
  const int t   = threadIdx.x;
  const size_t HH = 262144;
  const unsigned short* gpBase = Gp + (size_t)h * GSPLIT * HH;
  unsigned short* g = G + (size_t)h * HH;

  if (ti <= tj) {
    const int r  = t >> 2;
    const int cq = (t & 3) * 8;
    const size_t off = (size_t)(sr * 64 + r) * DHALF + sc * 32 + cq;
    float sum[8] = {};
    for (int s = 0; s < GSPLIT; ++s) {
      u16x8 v = *reinterpret_cast<const u16x8*>(gpBase + (size_t)s * HH + off);
      #pragma unroll
      for (int i = 0; i < 8; ++i) sum[i] += b2f(v[i]);
    }
    u16x8 o;
    #pragma unroll
    for (int i = 0; i < 8; ++i) o[i] = f2b(sum[i]);
    *reinterpret_cast<u16x8*>(g + off) = o;
  } else {
    const int a  = t >> 3;
    const int aq = (t & 7) * 8;
    const size_t soff = (size_t)(sc * 32 + a) * DHALF + sr * 64 + aq;
    float sum[8] = {};
    for (int s = 0; s < GSPLIT; ++s) {
      u16x8 v = *reinterpret_cast<const u16x8*>(gpBase + (size_t)s * HH + soff);
      #pragma unroll
      for (int i = 0; i < 8; ++i) sum[i] += b2f(v[i]);
    }
    #pragma unroll
    for (int i = 0; i < 8; ++i) T[a][aq + i] = f2b(sum[i]);
    __syncthreads();
    const int r  = t >> 2;
    const int cq = (t & 3) * 8;
    u16x8 o;
    #pragma unroll
    for (int i = 0; i < 8; ++i) o[i] = T[cq + i][r];
    *reinterpret_cast<u16x8*>(g + (size_t)(sr * 64 + r) * DHALF + sc * 32 + cq) = o;
  }
}

// ================= small GEMM 512^3: 4-buf, 1 barrier/iter, BK=128, nt=4 =================
__global__ __launch_bounds__(256) void k_s(const unsigned short* __restrict__ A,
                                           const unsigned short* __restrict__ B,
                                           unsigned short* __restrict__ C,
                                           long long hA, long long hB, long long hC) {
  const int o   = blockIdx.x + blockIdx.y * 8 + blockIdx.z * 64;
  const int swz = (o & 7) * 16 + (o >> 3);
  const int bx = swz & 7, by = (swz >> 3) & 7, bz = swz >> 6;

  const unsigned short* Ab = A + (size_t)bz * hA;
  const unsigned short* Bb = B + (size_t)bz * hB;
  unsigned short* Cb = C + (size_t)bz * hC;
  const int n0 = bx * 64;
  const int m0 = by * 64;

  __shared__ __align__(16) unsigned short lds[4][2][4][64 * 32];   // 128 KB

  const int tid  = threadIdx.x;
  const int lane = tid & 63;
  const int wave = tid >> 6;
  const int wm = (wave >> 1) * 32;
  const int wn = (wave & 1) * 32;
  const int fr = lane & 15;
  const int kg = (lane >> 4) * 8;

  const int srow = lane >> 2;
  const int scol = (lane & 3) * 8;
  const unsigned short* gA = Ab + (size_t)(m0 + srow) * DHALF + wave * 32 + scol;
  const unsigned short* gB = Bb + (size_t)(n0 + srow) * DHALF + wave * 32 + scol;

  f32x4 acc[2][2] = {};

  auto STAGE = [&](int buf, int t) {      // 8 loads/wave
    const int kofs = t * 128;
    #pragma unroll
    for (int j = 0; j < 4; ++j) {
      load_lds16(gA + kofs + j * 16 * DHALF, &lds[buf][0][wave][j * 512]);
      load_lds16(gB + kofs + j * 16 * DHALF, &lds[buf][1][wave][j * 512]);
    }
  };
  auto COMPUTE = [&](int buf) {
    #pragma unroll
    for (int p = 0; p < 4; ++p) {
      bf16x8 a0 = *reinterpret_cast<const bf16x8*>(&lds[buf][0][p][(wm + fr) * 32 + kg]);
      bf16x8 a1 = *reinterpret_cast<const bf16x8*>(&lds[buf][0][p][(wm + 16 + fr) * 32 + kg]);
      bf16x8 b0 = *reinterpret_cast<const bf16x8*>(&lds[buf][1][p][(wn + fr) * 32 + kg]);
      bf16x8 b1 = *reinterpret_cast<const bf16x8*>(&lds[buf][1][p][(wn + 16 + fr) * 32 + kg]);
      acc[0][0] = __builtin_amdgcn_mfma_f32_16x16x32_bf16(a0, b0, acc[0][0], 0, 0, 0);
      acc[0][1] = __builtin_amdgcn_mfma_f32_16x16x32_bf16(a0, b1, acc[0][1], 0, 0, 0);
      acc[1][0] = __builtin_amdgcn_mfma_f32_16x16x32_bf16(a1, b0, acc[1][0], 0, 0, 0);
      acc[1][1] = __builtin_amdgcn_mfma_f32_16x16x32_bf16(a1, b1, acc[1][1], 0, 0, 0);
    }
  };

  STAGE(0, 0); STAGE(1, 1);
  int bufS = 2, bufC = 0;
  for (int t = 0; t < 2; ++t) {           // nt = 4, ONE barrier/iter
    STAGE(bufS, t + 2); bufS = b4inc(bufS);
    vmwait<16>(); barx();
    COMPUTE(bufC); bufC = b4inc(bufC);
  }
  vmwait<8>(); barx();
  COMPUTE(bufC); bufC = b4inc(bufC);
  vmwait<0>(); barx();
  COMPUTE(bufC);

  #pragma unroll
  for (int fm = 0; fm < 2; ++fm)
    #pragma unroll
    for (int fn = 0; fn < 2; ++fn)
      #pragma unroll
      for (int r = 0; r < 4; ++r) {
        int row = m0 + wm + fm * 16 + (lane >> 4) * 4 + r;
        int col = n0 + wn + fn * 16 + fr;
        Cb[(size_t)row * DHALF + col] = f2b(acc[fm][fn][r]);
      }
}

// ================= final: out = X_h * M_h; 128x64 tiles, 512 blocks; 4-buf, 1 barrier/iter =================
__global__ __launch_bounds__(256) void k_final(const unsigned short* __restrict__ xb,
                                               const unsigned short* __restrict__ MT,
                                               float* __restrict__ out) {
  const int o   = blockIdx.x + blockIdx.y * 8 + blockIdx.z * 256;
  const int swz = (o & 7) * 64 + (o >> 3);
  const int bx = swz & 7, by = (swz >> 3) & 31, bz = swz >> 8;

  const unsigned short* MTh = MT + (size_t)bz * 262144;
  const int hoff = bz * DHALF;
  const int n0 = bx * 64;
  const int m0 = by * 128;

  __shared__ __align__(16) unsigned short SH[4][6144];  // per buf: A 4096 + B 2048 (48 KB)

  const int tid  = threadIdx.x;
  const int lane = tid & 63;
  const int wave = tid >> 6;
  const int wm = (wave >> 1) * 64;
  const int wn = (wave & 1) * 32;
  const int fr = lane & 15;
  const int kg = (lane >> 4) * 8;

  const int srow = wave * 32 + (lane >> 2);
  const int scol = (lane & 3) * 8;
  const unsigned short* gA0 = xb + (size_t)(m0 + srow) * D_FULL + hoff + scol;
  const unsigned short* gA1 = gA0 + (size_t)16 * D_FULL;
  const int brow = wave * 16 + (lane >> 2);
  const unsigned short* gB = MTh + (size_t)(n0 + brow) * DHALF + scol;

  f32x4 acc[4][2] = {};

  auto STAGE = [&](int buf, int t) {      // 3 loads/wave
    const int kofs = t * 32;
    unsigned short* Abuf = &SH[buf][0];
    unsigned short* Bbuf = &SH[buf][4096];
    load_lds16(gA0 + kofs, Abuf + wave * 1024);
    load_lds16(gA1 + kofs, Abuf + wave * 1024 + 512);
    load_lds16(gB + kofs, Bbuf + wave * 512);
  };
  auto COMPUTE = [&](int buf) {
    unsigned short* Abuf = &SH[buf][0];
    unsigned short* Bbuf = &SH[buf][4096];
    bf16x8 af[4], bv[2];
    #pragma unroll
    for (int f = 0; f < 4; ++f)
      af[f] = *reinterpret_cast<const bf16x8*>(&Abuf[(wm + f * 16 + fr) * 32 + kg]);
    #pragma unroll
    for (int f = 0; f < 2; ++f)
      bv[f] = *reinterpret_cast<const bf16x8*>(&Bbuf[(wn + f * 16 + fr) * 32 + kg]);
    #pragma unroll
    for (int fm = 0; fm < 4; ++fm)
      #pragma unroll
      for (int fn = 0; fn < 2; ++fn)
        acc[fm][fn] = __builtin_amdgcn_mfma_f32_16x16x32_bf16(af[fm], bv[fn], acc[fm][fn], 0, 0, 0);
  };

  STAGE(0, 0); STAGE(1, 1);
  int bufS = 2, bufC = 0;
  for (int t = 0; t < 14; ++t) {          // nt = 16, ONE barrier/iter
    STAGE(bufS, t + 2); bufS = b4inc(bufS);
    vmwait<6>(); barx();
    COMPUTE(bufC); bufC = b4inc(bufC);
  }
  vmwait<3>(); barx();
  COMPUTE(bufC); bufC = b4inc(bufC);
  vmwait<0>(); barx();
  COMPUTE(bufC);

  #pragma unroll
  for (int fm = 0; fm < 4; ++fm)
    #pragma unroll
    for (int fn = 0; fn < 2; ++fn)
      #pragma unroll
      for (int r = 0; r < 4; ++r) {
        int row = m0 + wm + fm * 16 + (lane >> 4) * 4 + r;
        int col = hoff + n0 + wn + fn * 16 + fr;
        out[(size_t)row * D_FULL + col] = acc[fm][fn][r];
      }
}

extern "C" void kernel_launch(void* const* d_in, const int* in_sizes, int n_in,
                              void* d_out, int out_size, void* d_ws, size_t ws_size,
                              hipStream_t stream) {
  const float* x   = (const float*)d_in[0];
  const float* Wq1 = (const float*)d_in[1];
  const float* Wq2 = (const float*)d_in[2];
  const float* Wk1 = (const float*)d_in[3];
  const float* Wk2 = (const float*)d_in[4];
  const float* Wv1 = (const float*)d_in[5];
  const float* Wv2 = (const float*)d_in[6];
  float* out = (float*)d_out;

  // workspace layout (ushort elements), ~36 MB
  unsigned short* ws  = (unsigned short*)d_ws;
  unsigned short* xb  = ws;                    // [4096][1024]
  unsigned short* xT  = ws + 4194304;          // [1024][4096]
  unsigned short* Wb  = ws + 8388608;          // 6x[512][512] (only v written)
  unsigned short* WbT = ws + 9961472;          // transposes (only q,k written)
  unsigned short* G   = ws + 11534336;         // [2][512][512]
  unsigned short* P   = ws + 12058624;         // [2][512][512]
  unsigned short* TT  = ws + 12582912;         // [2][512][512]
  unsigned short* MT  = ws + 13107200;         // [2][512][512]
  unsigned short* Gp  = ws + 13631488;         // [2*GSPLIT][512][512] bf16 partials (upper tiles only)

  const long long HH = 262144;

  k_cvt_all<<<1408, 256, 0, stream>>>(x, Wq1, Wq2, Wk1, Wk2, Wv1, Wv2, xb, xT, Wb, WbT);

  // P (4 per XCD chunk, first) + gram upper-triangle pairs (20 per chunk); 192 blocks
  k_gp<<<192, 256, 0, stream>>>(xT, WbT, Gp, P);

  // reduce + symmetric reconstruction
  k_gred<<<256, 256, 0, stream>>>(Gp, G);

  // TT = Wv * G  (G symmetric)
  k_s<<<dim3(8, 8, 2), 256, 0, stream>>>(Wb + 4 * HH, G, TT, HH, HH, HH);
  // MT = TT * P^T
  k_s<<<dim3(8, 8, 2), 256, 0, stream>>>(TT, P, MT, HH, HH, HH);

  // out = X_h * M_h  (128x64 tiles, 2 blocks/CU — champion R10 geometry)
  k_final<<<dim3(8, 32, 2), 256, 0, stream>>>(xb, MT, out);
}